// Round 6
// baseline (53.373 us; speedup 1.0000x reference)
//
#include <hip/hip_runtime.h>

// LIF forward over time-major x: (T=16, B=128, N=16384) fp32.
//   m[t] = 0.5*v[t-1] + x[t];  y[t] = (m >= 1.0);  v[t] = m*(1-y[t])
// R6: flip the cache policy. x+y = 268 MB > 256 MB LLC, so one array
// must miss. Make x loads NONTEMPORAL (no LLC allocate) and y stores
// PLAIN (cached): y (131 MB) stays LLC-resident across graph replays,
// its dirty lines are rewritten in place and never reach HBM.
// Steady-state HBM traffic ~= x reads (134 MB) only.

#define LIF_T 16
#define TAU 0.5f
#define VTH 1.0f

typedef float fx4 __attribute__((ext_vector_type(4)));

__global__ __launch_bounds__(256) void lif_fwd_kernel(
    const fx4* __restrict__ x, fx4* __restrict__ y, int cols) {
    int i = blockIdx.x * blockDim.x + threadIdx.x;
    if (i >= cols) return;

    fx4 v = {0.0f, 0.0f, 0.0f, 0.0f};
    size_t idx = (size_t)i;

#pragma unroll
    for (int t = 0; t < LIF_T; ++t) {
        fx4 xt = __builtin_nontemporal_load(&x[idx]);

        fx4 m = v * TAU + xt;

        fx4 out;
        out.x = (m.x >= VTH) ? 1.0f : 0.0f;
        out.y = (m.y >= VTH) ? 1.0f : 0.0f;
        out.z = (m.z >= VTH) ? 1.0f : 0.0f;
        out.w = (m.w >= VTH) ? 1.0f : 0.0f;

        v.x = (m.x >= VTH) ? 0.0f : m.x;   // hard reset
        v.y = (m.y >= VTH) ? 0.0f : m.y;
        v.z = (m.z >= VTH) ? 0.0f : m.z;
        v.w = (m.w >= VTH) ? 0.0f : m.w;

        y[idx] = out;   // cached store: y stays LLC-resident
        idx += (size_t)cols;
    }
}

extern "C" void kernel_launch(void* const* d_in, const int* in_sizes, int n_in,
                              void* d_out, int out_size, void* d_ws, size_t ws_size,
                              hipStream_t stream) {
    const fx4* x = (const fx4*)d_in[0];
    fx4* y = (fx4*)d_out;

    int total = in_sizes[0];
    int cols = total / LIF_T / 4;   // float4 columns per time plane

    const int block = 256;
    int grid = (cols + block - 1) / block;
    lif_fwd_kernel<<<grid, block, 0, stream>>>(x, y, cols);
}

// Round 7
// 51.482 us; speedup vs baseline: 1.0367x; 1.0367x over previous
//
#include <hip/hip_runtime.h>

// LIF forward over time-major x: (T=16, B=128, N=16384) fp32.
//   m[t] = 0.5*v[t-1] + x[t];  y[t] = (m >= 1.0);  v[t] = m*(1-y[t])
// R7: force 16 outstanding loads/wave via inline-asm global_load_dwordx4
// + counted s_waitcnt vmcnt(15-t) (+ sched_barrier(0), rule #18).
// Outputs reuse the input registers; all 16 nt stores batched at the end
// so the counted load queue never contains stores.
// Cache policy per R3 (best): cached loads (LLC serves ~half of x),
// nontemporal stores (no write-allocate).

#define TAU 0.5f
#define VTH 1.0f

typedef float fx4 __attribute__((ext_vector_type(4)));

__global__ __launch_bounds__(256) void lif_fwd_kernel(
    const fx4* __restrict__ x, fx4* __restrict__ y, int cols) {
    int i = blockIdx.x * blockDim.x + threadIdx.x;
    if (i >= cols) return;

    size_t idx = (size_t)i;
    size_t stride = (size_t)cols;

    fx4 d0, d1, d2, d3, d4, d5, d6, d7, d8, d9, d10, d11, d12, d13, d14, d15;

#define LIF_LOAD(T) \
    asm volatile("global_load_dwordx4 %0, %1, off" \
                 : "=&v"(d##T) : "v"(x + idx + (size_t)(T) * stride))

    LIF_LOAD(0);  LIF_LOAD(1);  LIF_LOAD(2);  LIF_LOAD(3);
    LIF_LOAD(4);  LIF_LOAD(5);  LIF_LOAD(6);  LIF_LOAD(7);
    LIF_LOAD(8);  LIF_LOAD(9);  LIF_LOAD(10); LIF_LOAD(11);
    LIF_LOAD(12); LIF_LOAD(13); LIF_LOAD(14); LIF_LOAD(15);

    fx4 v = {0.0f, 0.0f, 0.0f, 0.0f};

    // Wait for load T (in-order vmcnt retirement), then LIF step; the
    // spike output overwrites d##T so peak liveness stays 16 fx4.
#define LIF_STEP(T, W) \
    do { \
        asm volatile("s_waitcnt vmcnt(" #W ")" ::: "memory"); \
        __builtin_amdgcn_sched_barrier(0); \
        fx4 m = v * TAU + d##T; \
        fx4 o; \
        o.x = (m.x >= VTH) ? 1.0f : 0.0f; \
        o.y = (m.y >= VTH) ? 1.0f : 0.0f; \
        o.z = (m.z >= VTH) ? 1.0f : 0.0f; \
        o.w = (m.w >= VTH) ? 1.0f : 0.0f; \
        v.x = (m.x >= VTH) ? 0.0f : m.x; \
        v.y = (m.y >= VTH) ? 0.0f : m.y; \
        v.z = (m.z >= VTH) ? 0.0f : m.z; \
        v.w = (m.w >= VTH) ? 0.0f : m.w; \
        d##T = o; \
    } while (0)

    LIF_STEP(0, 15);  LIF_STEP(1, 14);  LIF_STEP(2, 13);  LIF_STEP(3, 12);
    LIF_STEP(4, 11);  LIF_STEP(5, 10);  LIF_STEP(6, 9);   LIF_STEP(7, 8);
    LIF_STEP(8, 7);   LIF_STEP(9, 6);   LIF_STEP(10, 5);  LIF_STEP(11, 4);
    LIF_STEP(12, 3);  LIF_STEP(13, 2);  LIF_STEP(14, 1);  LIF_STEP(15, 0);

#define LIF_STORE(T) \
    __builtin_nontemporal_store(d##T, &y[idx + (size_t)(T) * stride])

    LIF_STORE(0);  LIF_STORE(1);  LIF_STORE(2);  LIF_STORE(3);
    LIF_STORE(4);  LIF_STORE(5);  LIF_STORE(6);  LIF_STORE(7);
    LIF_STORE(8);  LIF_STORE(9);  LIF_STORE(10); LIF_STORE(11);
    LIF_STORE(12); LIF_STORE(13); LIF_STORE(14); LIF_STORE(15);
}

extern "C" void kernel_launch(void* const* d_in, const int* in_sizes, int n_in,
                              void* d_out, int out_size, void* d_ws, size_t ws_size,
                              hipStream_t stream) {
    const fx4* x = (const fx4*)d_in[0];
    fx4* y = (fx4*)d_out;

    int total = in_sizes[0];
    int cols = total / 16 / 4;   // float4 columns per time plane

    const int block = 256;
    int grid = (cols + block - 1) / block;
    lif_fwd_kernel<<<grid, block, 0, stream>>>(x, y, cols);
}

// Round 8
// 46.170 us; speedup vs baseline: 1.1560x; 1.1150x over previous
//
#include <hip/hip_runtime.h>

// LIF forward over time-major x: (T=16, B=128, N=16384) fp32.
//   m[t] = 0.5*v[t-1] + x[t];  y[t] = (m >= 1.0);  v[t] = m*(1-y[t])
// R8: discriminating probe on the store cache policy. Builtin nt store
// (bare `nt` bit) left FETCH at exactly half of x -> either TCC sector
// accounting (we're at roofline) or y still allocates in the memory-side
// Infinity Cache and evicts x. Emit stores as `sc0 sc1 nt` (system-scope
// nontemporal = strongest bypass encoding) to discriminate.
// Structure otherwise = R3 best (cached loads, 1 float4 col/thread).

#define LIF_T 16
#define TAU 0.5f
#define VTH 1.0f

typedef float fx4 __attribute__((ext_vector_type(4)));

__global__ __launch_bounds__(256) void lif_fwd_kernel(
    const fx4* __restrict__ x, fx4* __restrict__ y, int cols) {
    int i = blockIdx.x * blockDim.x + threadIdx.x;
    if (i >= cols) return;

    fx4 v = {0.0f, 0.0f, 0.0f, 0.0f};
    size_t idx = (size_t)i;

#pragma unroll
    for (int t = 0; t < LIF_T; ++t) {
        fx4 xt = x[idx];

        fx4 m = v * TAU + xt;

        fx4 out;
        out.x = (m.x >= VTH) ? 1.0f : 0.0f;
        out.y = (m.y >= VTH) ? 1.0f : 0.0f;
        out.z = (m.z >= VTH) ? 1.0f : 0.0f;
        out.w = (m.w >= VTH) ? 1.0f : 0.0f;

        v.x = (m.x >= VTH) ? 0.0f : m.x;   // hard reset
        v.y = (m.y >= VTH) ? 0.0f : m.y;
        v.z = (m.z >= VTH) ? 0.0f : m.z;
        v.w = (m.w >= VTH) ? 0.0f : m.w;

        // system-scope nontemporal store: bypass L2 AND Infinity Cache.
        // No "memory" clobber: x/y don't alias, let next loads hoist.
        asm volatile("global_store_dwordx4 %0, %1, off sc0 sc1 nt"
                     :: "v"(&y[idx]), "v"(out));

        idx += (size_t)cols;
    }
}

extern "C" void kernel_launch(void* const* d_in, const int* in_sizes, int n_in,
                              void* d_out, int out_size, void* d_ws, size_t ws_size,
                              hipStream_t stream) {
    const fx4* x = (const fx4*)d_in[0];
    fx4* y = (fx4*)d_out;

    int total = in_sizes[0];
    int cols = total / LIF_T / 4;   // float4 columns per time plane

    const int block = 256;
    int grid = (cols + block - 1) / block;
    lif_fwd_kernel<<<grid, block, 0, stream>>>(x, y, cols);
}